// Round 1
// baseline (884.377 us; speedup 1.0000x reference)
//
#include <hip/hip_runtime.h>
#include <hip/hip_bf16.h>

// Problem constants (B=1)
#define L_SEQ   2048
#define D_MODEL 512
#define D_INNER 1024
#define D_STATE 16
#define DT_RANK 32

// ---------------------------------------------------------------------------
// Generic tiled f32 GEMM:  C[m][n] = sum_k A[m*K+k] * B[n*K+k]   (NT layout)
// Block = 256 threads as 16x16, each thread computes TM x TN outputs.
// ---------------------------------------------------------------------------
template<int BM, int BN, int BK, int TM, int TN>
__global__ __launch_bounds__(256)
void gemm_nt(const float* __restrict__ A, const float* __restrict__ B,
             float* __restrict__ C, int M, int N, int K, int ldc) {
    __shared__ float As[BK][BM + 4];
    __shared__ float Bs[BK][BN + 4];

    const int tid = threadIdx.x;
    const int tx = tid & 15;          // 0..15 -> columns
    const int ty = tid >> 4;          // 0..15 -> rows
    const int m0 = blockIdx.y * BM;
    const int n0 = blockIdx.x * BN;

    float acc[TM][TN];
#pragma unroll
    for (int i = 0; i < TM; i++)
#pragma unroll
        for (int j = 0; j < TN; j++) acc[i][j] = 0.f;

    constexpr int A_PASS = (BM * BK) / (256 * 4);
    constexpr int B_PASS = (BN * BK) / (256 * 4);

    for (int k0 = 0; k0 < K; k0 += BK) {
        __syncthreads();   // protect LDS from previous iteration's readers
#pragma unroll
        for (int p = 0; p < A_PASS; p++) {
            int idx = p * 256 + tid;
            int row = idx / (BK / 4);
            int kq  = idx % (BK / 4);
            float4 v = *(const float4*)(A + (size_t)(m0 + row) * K + k0 + kq * 4);
            As[kq * 4 + 0][row] = v.x;
            As[kq * 4 + 1][row] = v.y;
            As[kq * 4 + 2][row] = v.z;
            As[kq * 4 + 3][row] = v.w;
        }
#pragma unroll
        for (int p = 0; p < B_PASS; p++) {
            int idx = p * 256 + tid;
            int row = idx / (BK / 4);
            int kq  = idx % (BK / 4);
            float4 v = *(const float4*)(B + (size_t)(n0 + row) * K + k0 + kq * 4);
            Bs[kq * 4 + 0][row] = v.x;
            Bs[kq * 4 + 1][row] = v.y;
            Bs[kq * 4 + 2][row] = v.z;
            Bs[kq * 4 + 3][row] = v.w;
        }
        __syncthreads();

#pragma unroll
        for (int kk = 0; kk < BK; kk++) {
            float a[TM], b[TN];
#pragma unroll
            for (int i = 0; i < TM; i += 4)
                *(float4*)&a[i] = *(const float4*)&As[kk][ty * TM + i];
#pragma unroll
            for (int j = 0; j < TN; j += 4)
                *(float4*)&b[j] = *(const float4*)&Bs[kk][tx * TN + j];
#pragma unroll
            for (int i = 0; i < TM; i++)
#pragma unroll
                for (int j = 0; j < TN; j++)
                    acc[i][j] = fmaf(a[i], b[j], acc[i][j]);
        }
    }

#pragma unroll
    for (int i = 0; i < TM; i++) {
        float* crow = C + (size_t)(m0 + ty * TM + i) * ldc + n0 + tx * TN;
#pragma unroll
        for (int j = 0; j < TN; j += 4) {
            *(float4*)(crow + j) = make_float4(acc[i][j], acc[i][j + 1],
                                               acc[i][j + 2], acc[i][j + 3]);
        }
    }
}

// ---------------------------------------------------------------------------
// Causal depthwise conv (4 taps) + SiLU.  xp lives in xz[:, 0:1024].
// One thread per (l, 4 channels).
// ---------------------------------------------------------------------------
__global__ __launch_bounds__(256)
void conv_silu_kernel(const float* __restrict__ xz,
                      const float* __restrict__ w,   // [1024][4]
                      const float* __restrict__ b,   // [1024]
                      float* __restrict__ xpc) {
    int gid = blockIdx.x * 256 + threadIdx.x;       // L*256 total
    int l  = gid >> 8;
    int dq = gid & 255;
    int d  = dq * 4;

    // weights: row per channel, exactly one float4 each
    float4 w0 = ((const float4*)w)[d + 0];
    float4 w1 = ((const float4*)w)[d + 1];
    float4 w2 = ((const float4*)w)[d + 2];
    float4 w3 = ((const float4*)w)[d + 3];
    float4 bv = ((const float4*)b)[dq];

    float4 zf = make_float4(0.f, 0.f, 0.f, 0.f);
    float4 x0 = (l >= 3) ? *(const float4*)(xz + (size_t)(l - 3) * 2048 + d) : zf;
    float4 x1 = (l >= 2) ? *(const float4*)(xz + (size_t)(l - 2) * 2048 + d) : zf;
    float4 x2 = (l >= 1) ? *(const float4*)(xz + (size_t)(l - 1) * 2048 + d) : zf;
    float4 x3 =            *(const float4*)(xz + (size_t)(l    ) * 2048 + d);

    float4 r;
    r.x = bv.x + x0.x * w0.x + x1.x * w0.y + x2.x * w0.z + x3.x * w0.w;
    r.y = bv.y + x0.y * w1.x + x1.y * w1.y + x2.y * w1.z + x3.y * w1.w;
    r.z = bv.z + x0.z * w2.x + x1.z * w2.y + x2.z * w2.z + x3.z * w2.w;
    r.w = bv.w + x0.w * w3.x + x1.w * w3.y + x2.w * w3.z + x3.w * w3.w;

    r.x = r.x / (1.f + expf(-r.x));
    r.y = r.y / (1.f + expf(-r.y));
    r.z = r.z / (1.f + expf(-r.z));
    r.w = r.w / (1.f + expf(-r.w));

    *(float4*)(xpc + (size_t)l * 1024 + d) = r;
}

// ---------------------------------------------------------------------------
// Fused x_proj + dt_proj + softplus.  One block (256 thr) per sequence pos l.
// Emits delta[l][1024], Bc[l][16], Cc[l][16].
// ---------------------------------------------------------------------------
__global__ __launch_bounds__(256)
void xdbl_delta_kernel(const float* __restrict__ xpc,
                       const float* __restrict__ xw,   // x_proj_w [64][1024]
                       const float* __restrict__ dtw,  // dt_proj_w [1024][32]
                       const float* __restrict__ dtb,  // dt_proj_b [1024]
                       float* __restrict__ delta,
                       float* __restrict__ Bc, float* __restrict__ Cc) {
    const int l = blockIdx.x;
    const int tid = threadIdx.x;
    __shared__ float sx[1024];
    __shared__ float sred[4][64];
    __shared__ float sdbl[64];

    ((float4*)sx)[tid] = ((const float4*)(xpc + (size_t)l * 1024))[tid];
    __syncthreads();

    // x_dbl[e] = dot(sx, xw[e]);  e = tid&63, 4-way split over K
    {
        int e = tid & 63, part = tid >> 6;
        const float* wrow = xw + (size_t)e * 1024 + part * 256;
        const float* xrow = sx + part * 256;
        float s = 0.f;
#pragma unroll 8
        for (int k = 0; k < 256; k += 4) {
            float4 wv = *(const float4*)(wrow + k);
            s += wv.x * xrow[k] + wv.y * xrow[k + 1] + wv.z * xrow[k + 2] + wv.w * xrow[k + 3];
        }
        sred[part][e] = s;
    }
    __syncthreads();
    if (tid < 64) {
        float v = sred[0][tid] + sred[1][tid] + sred[2][tid] + sred[3][tid];
        sdbl[tid] = v;
        if (tid >= 32 && tid < 48) Bc[(size_t)l * 16 + (tid - 32)] = v;
        if (tid >= 48)             Cc[(size_t)l * 16 + (tid - 48)] = v;
    }
    __syncthreads();

#pragma unroll
    for (int q = 0; q < 4; q++) {
        int d = tid + q * 256;
        float a = dtb[d];
        const float* wr = dtw + (size_t)d * 32;
#pragma unroll
        for (int r = 0; r < 32; r += 4) {
            float4 wv = *(const float4*)(wr + r);
            a += wv.x * sdbl[r] + wv.y * sdbl[r + 1] + wv.z * sdbl[r + 2] + wv.w * sdbl[r + 3];
        }
        // softplus, stable form (matches jax.nn.softplus)
        float sp = fmaxf(a, 0.f) + log1pf(expf(-fabsf(a)));
        delta[(size_t)l * 1024 + d] = sp;
    }
}

// ---------------------------------------------------------------------------
// Selective scan, matching the reference's parallel formulation exactly:
//   h_t = dA_t*h_{t-1} + dA_t*g_{t-1}*(delta*B*x)_t ;  g = cA/(cA+1e-8),
//   cA = prod(max(dA,1e-6)).
// One wave per 4 channels; lane = (d_local<<4)|n.  Chunked LDS staging.
// Fuses  y = sum_n h*C + x*D  and  out_pre = y*silu(z).
// ---------------------------------------------------------------------------
__global__ __launch_bounds__(64)
void scan_kernel(const float* __restrict__ delta,
                 const float* __restrict__ xpc,
                 const float* __restrict__ xz,    // z at cols [1024,2048)
                 const float* __restrict__ Bc, const float* __restrict__ Cc,
                 const float* __restrict__ A_log, const float* __restrict__ Dv,
                 float* __restrict__ outpre) {
    const int lane = threadIdx.x;
    const int d0 = blockIdx.x * 4;
    const int dl = lane >> 4;
    const int n  = lane & 15;
    const int d  = d0 + dl;

    const float Aneg = -expf(A_log[d * D_STATE + n]);
    const float Dd   = Dv[d];
    float h = 0.f, cA = 1.f;

    __shared__ float s_dlt[128][4], s_x[128][4], s_z[128][4], s_y[128][4];
    __shared__ float s_B[128][16], s_C[128][16];

    for (int c = 0; c < L_SEQ / 128; c++) {
        const int lb = c * 128;
        __syncthreads();
        for (int t = lane; t < 128; t += 64) {
            *(float4*)&s_dlt[t][0] = *(const float4*)(delta + (size_t)(lb + t) * 1024 + d0);
            *(float4*)&s_x[t][0]   = *(const float4*)(xpc   + (size_t)(lb + t) * 1024 + d0);
            *(float4*)&s_z[t][0]   = *(const float4*)(xz    + (size_t)(lb + t) * 2048 + 1024 + d0);
        }
        for (int i = lane; i < 512; i += 64) {
            ((float4*)&s_B[0][0])[i] = ((const float4*)(Bc + (size_t)lb * 16))[i];
            ((float4*)&s_C[0][0])[i] = ((const float4*)(Cc + (size_t)lb * 16))[i];
        }
        __syncthreads();

#pragma unroll 4
        for (int t = 0; t < 128; t++) {
            float dlt = s_dlt[t][dl];
            float xv  = s_x[t][dl];
            float bv  = s_B[t][n];
            float dA  = fmaxf(expf(dlt * Aneg), 1e-6f);
            float g   = cA / (cA + 1e-8f);
            float inp = dlt * bv * xv;
            h  = dA * h + (dA * g) * inp;
            cA = cA * dA;
            float p = h * s_C[t][n];
            p += __shfl_xor(p, 1);
            p += __shfl_xor(p, 2);
            p += __shfl_xor(p, 4);
            p += __shfl_xor(p, 8);
            if (n == 0) {
                float zv = s_z[t][dl];
                float sz = zv / (1.f + expf(-zv));
                s_y[t][dl] = (p + xv * Dd) * sz;
            }
        }
        __syncthreads();
        for (int t = lane; t < 128; t += 64) {
            *(float4*)(outpre + (size_t)(lb + t) * 1024 + d0) = *(const float4*)&s_y[t][0];
        }
    }
}

// ---------------------------------------------------------------------------
extern "C" void kernel_launch(void* const* d_in, const int* in_sizes, int n_in,
                              void* d_out, int out_size, void* d_ws, size_t ws_size,
                              hipStream_t stream) {
    const float* x          = (const float*)d_in[0];
    const float* in_proj_w  = (const float*)d_in[1];
    const float* conv_w     = (const float*)d_in[2];
    const float* conv_b     = (const float*)d_in[3];
    const float* x_proj_w   = (const float*)d_in[4];
    const float* dt_proj_w  = (const float*)d_in[5];
    const float* dt_proj_b  = (const float*)d_in[6];
    const float* A_log      = (const float*)d_in[7];
    const float* Dv         = (const float*)d_in[8];
    const float* out_proj_w = (const float*)d_in[9];
    float* out = (float*)d_out;
    float* ws  = (float*)d_ws;

    // workspace layout (floats):
    float* xz    = ws;                 // [2048][2048]  xp | z
    float* xpc   = ws + 4194304;       // [2048][1024]
    float* delta = ws + 6291456;       // [2048][1024]  (reused as out_pre)
    float* Bcol  = ws + 8388608;       // [2048][16]
    float* Ccol  = ws + 8421376;       // [2048][16]

    // 1. in_proj: xz = x @ in_proj_w^T   (M=2048, N=2048, K=512)
    gemm_nt<128, 128, 16, 8, 8><<<dim3(2048 / 128, 2048 / 128), 256, 0, stream>>>(
        x, in_proj_w, xz, L_SEQ, 2 * D_INNER, D_MODEL, 2 * D_INNER);

    // 2. depthwise causal conv + silu
    conv_silu_kernel<<<L_SEQ, 256, 0, stream>>>(xz, conv_w, conv_b, xpc);

    // 3. x_proj + dt_proj + softplus
    xdbl_delta_kernel<<<L_SEQ, 256, 0, stream>>>(xpc, x_proj_w, dt_proj_w, dt_proj_b,
                                                 delta, Bcol, Ccol);

    // 4. selective scan (+ D skip, * silu(z)); out_pre aliases delta
    scan_kernel<<<D_INNER / 4, 64, 0, stream>>>(delta, xpc, xz, Bcol, Ccol,
                                                A_log, Dv, delta);

    // 5. out_proj: out = out_pre @ out_proj_w^T  (M=2048, N=512, K=1024)
    gemm_nt<64, 64, 32, 4, 4><<<dim3(512 / 64, 2048 / 64), 256, 0, stream>>>(
        delta, out_proj_w, out, L_SEQ, D_MODEL, D_INNER, D_MODEL);
}

// Round 2
// 350.769 us; speedup vs baseline: 2.5212x; 2.5212x over previous
//
#include <hip/hip_runtime.h>
#include <hip/hip_bf16.h>

// Problem constants (B=1)
#define L_SEQ   2048
#define D_MODEL 512
#define D_INNER 1024
#define D_STATE 16
#define DT_RANK 32

// ---------------------------------------------------------------------------
// Generic tiled f32 GEMM:  C[m][n] = sum_k A[m*K+k] * B[n*K+k]   (NT layout)
// Block = 256 threads as 16x16, each thread computes TM x TN outputs.
// ---------------------------------------------------------------------------
template<int BM, int BN, int BK, int TM, int TN>
__global__ __launch_bounds__(256)
void gemm_nt(const float* __restrict__ A, const float* __restrict__ B,
             float* __restrict__ C, int M, int N, int K, int ldc) {
    __shared__ float As[BK][BM + 4];
    __shared__ float Bs[BK][BN + 4];

    const int tid = threadIdx.x;
    const int tx = tid & 15;          // 0..15 -> columns
    const int ty = tid >> 4;          // 0..15 -> rows
    const int m0 = blockIdx.y * BM;
    const int n0 = blockIdx.x * BN;

    float acc[TM][TN];
#pragma unroll
    for (int i = 0; i < TM; i++)
#pragma unroll
        for (int j = 0; j < TN; j++) acc[i][j] = 0.f;

    constexpr int A_PASS = (BM * BK) / (256 * 4);
    constexpr int B_PASS = (BN * BK) / (256 * 4);

    for (int k0 = 0; k0 < K; k0 += BK) {
        __syncthreads();   // protect LDS from previous iteration's readers
#pragma unroll
        for (int p = 0; p < A_PASS; p++) {
            int idx = p * 256 + tid;
            int row = idx / (BK / 4);
            int kq  = idx % (BK / 4);
            float4 v = *(const float4*)(A + (size_t)(m0 + row) * K + k0 + kq * 4);
            As[kq * 4 + 0][row] = v.x;
            As[kq * 4 + 1][row] = v.y;
            As[kq * 4 + 2][row] = v.z;
            As[kq * 4 + 3][row] = v.w;
        }
#pragma unroll
        for (int p = 0; p < B_PASS; p++) {
            int idx = p * 256 + tid;
            int row = idx / (BK / 4);
            int kq  = idx % (BK / 4);
            float4 v = *(const float4*)(B + (size_t)(n0 + row) * K + k0 + kq * 4);
            Bs[kq * 4 + 0][row] = v.x;
            Bs[kq * 4 + 1][row] = v.y;
            Bs[kq * 4 + 2][row] = v.z;
            Bs[kq * 4 + 3][row] = v.w;
        }
        __syncthreads();

#pragma unroll
        for (int kk = 0; kk < BK; kk++) {
            float a[TM], b[TN];
#pragma unroll
            for (int i = 0; i < TM; i += 4)
                *(float4*)&a[i] = *(const float4*)&As[kk][ty * TM + i];
#pragma unroll
            for (int j = 0; j < TN; j += 4)
                *(float4*)&b[j] = *(const float4*)&Bs[kk][tx * TN + j];
#pragma unroll
            for (int i = 0; i < TM; i++)
#pragma unroll
                for (int j = 0; j < TN; j++)
                    acc[i][j] = fmaf(a[i], b[j], acc[i][j]);
        }
    }

#pragma unroll
    for (int i = 0; i < TM; i++) {
        float* crow = C + (size_t)(m0 + ty * TM + i) * ldc + n0 + tx * TN;
#pragma unroll
        for (int j = 0; j < TN; j += 4) {
            *(float4*)(crow + j) = make_float4(acc[i][j], acc[i][j + 1],
                                               acc[i][j + 2], acc[i][j + 3]);
        }
    }
}

// ---------------------------------------------------------------------------
// Causal depthwise conv (4 taps) + SiLU.  xp lives in xz[:, 0:1024].
// One thread per (l, 4 channels).
// ---------------------------------------------------------------------------
__global__ __launch_bounds__(256)
void conv_silu_kernel(const float* __restrict__ xz,
                      const float* __restrict__ w,   // [1024][4]
                      const float* __restrict__ b,   // [1024]
                      float* __restrict__ xpc) {
    int gid = blockIdx.x * 256 + threadIdx.x;       // L*256 total
    int l  = gid >> 8;
    int dq = gid & 255;
    int d  = dq * 4;

    float4 w0 = ((const float4*)w)[d + 0];
    float4 w1 = ((const float4*)w)[d + 1];
    float4 w2 = ((const float4*)w)[d + 2];
    float4 w3 = ((const float4*)w)[d + 3];
    float4 bv = ((const float4*)b)[dq];

    float4 zf = make_float4(0.f, 0.f, 0.f, 0.f);
    float4 x0 = (l >= 3) ? *(const float4*)(xz + (size_t)(l - 3) * 2048 + d) : zf;
    float4 x1 = (l >= 2) ? *(const float4*)(xz + (size_t)(l - 2) * 2048 + d) : zf;
    float4 x2 = (l >= 1) ? *(const float4*)(xz + (size_t)(l - 1) * 2048 + d) : zf;
    float4 x3 =            *(const float4*)(xz + (size_t)(l    ) * 2048 + d);

    float4 r;
    r.x = bv.x + x0.x * w0.x + x1.x * w0.y + x2.x * w0.z + x3.x * w0.w;
    r.y = bv.y + x0.y * w1.x + x1.y * w1.y + x2.y * w1.z + x3.y * w1.w;
    r.z = bv.z + x0.z * w2.x + x1.z * w2.y + x2.z * w2.z + x3.z * w2.w;
    r.w = bv.w + x0.w * w3.x + x1.w * w3.y + x2.w * w3.z + x3.w * w3.w;

    r.x = r.x / (1.f + expf(-r.x));
    r.y = r.y / (1.f + expf(-r.y));
    r.z = r.z / (1.f + expf(-r.z));
    r.w = r.w / (1.f + expf(-r.w));

    *(float4*)(xpc + (size_t)l * 1024 + d) = r;
}

// ---------------------------------------------------------------------------
// Fused x_proj + dt_proj + softplus.  One block (256 thr) per sequence pos l.
// ---------------------------------------------------------------------------
__global__ __launch_bounds__(256)
void xdbl_delta_kernel(const float* __restrict__ xpc,
                       const float* __restrict__ xw,   // x_proj_w [64][1024]
                       const float* __restrict__ dtw,  // dt_proj_w [1024][32]
                       const float* __restrict__ dtb,  // dt_proj_b [1024]
                       float* __restrict__ delta,
                       float* __restrict__ Bc, float* __restrict__ Cc) {
    const int l = blockIdx.x;
    const int tid = threadIdx.x;
    __shared__ float sx[1024];
    __shared__ float sred[4][64];
    __shared__ float sdbl[64];

    ((float4*)sx)[tid] = ((const float4*)(xpc + (size_t)l * 1024))[tid];
    __syncthreads();

    {
        int e = tid & 63, part = tid >> 6;
        const float* wrow = xw + (size_t)e * 1024 + part * 256;
        const float* xrow = sx + part * 256;
        float s = 0.f;
#pragma unroll 8
        for (int k = 0; k < 256; k += 4) {
            float4 wv = *(const float4*)(wrow + k);
            s += wv.x * xrow[k] + wv.y * xrow[k + 1] + wv.z * xrow[k + 2] + wv.w * xrow[k + 3];
        }
        sred[part][e] = s;
    }
    __syncthreads();
    if (tid < 64) {
        float v = sred[0][tid] + sred[1][tid] + sred[2][tid] + sred[3][tid];
        sdbl[tid] = v;
        if (tid >= 32 && tid < 48) Bc[(size_t)l * 16 + (tid - 32)] = v;
        if (tid >= 48)             Cc[(size_t)l * 16 + (tid - 48)] = v;
    }
    __syncthreads();

#pragma unroll
    for (int q = 0; q < 4; q++) {
        int d = tid + q * 256;
        float a = dtb[d];
        const float* wr = dtw + (size_t)d * 32;
#pragma unroll
        for (int r = 0; r < 32; r += 4) {
            float4 wv = *(const float4*)(wr + r);
            a += wv.x * sdbl[r] + wv.y * sdbl[r + 1] + wv.z * sdbl[r + 2] + wv.w * sdbl[r + 3];
        }
        float sp = fmaxf(a, 0.f) + log1pf(expf(-fabsf(a)));
        delta[(size_t)l * 1024 + d] = sp;
    }
}

// ---------------------------------------------------------------------------
// Chunked selective scan (3-phase, exact recomposition of the reference's
// parallel formulation):
//   h_t = dA_t*h_{t-1} + dA_t*g_{t-1}*(delta*B*x)_t ; g = cA/(cA+1e-8),
//   cA = prod(max(dA,1e-6)).
// Block = 1024 threads = 16 waves; wave w owns chunk w (128 steps) of the
// full L=2048 sequence for 4 channels. lane = (d_local<<4)|n.
// Phase A: per-chunk sum of clipped log-decay  -> chunk-start cA (LDS scan)
// Phase B: per-chunk local accumulation c_w    -> chunk-start h  (LDS scan)
// Phase C: final recurrence + C-contraction + x*D + silu(z) gate
// Output buffered in LDS, written after barrier (safe to alias delta).
// ---------------------------------------------------------------------------
#define CHUNK 128
#define NCHUNK 16

__global__ __launch_bounds__(1024)
void scan_kernel(const float* delta,
                 const float* __restrict__ xpc,
                 const float* __restrict__ xz,    // z at cols [1024,2048)
                 const float* __restrict__ Bc, const float* __restrict__ Cc,
                 const float* __restrict__ A_log, const float* __restrict__ Dv,
                 float* outpre) {
    const int tid  = threadIdx.x;
    const int w    = tid >> 6;          // chunk id 0..15
    const int lane = tid & 63;
    const int dl   = lane >> 4;
    const int n    = lane & 15;
    const int d0   = blockIdx.x * 4;
    const int d    = d0 + dl;
    const int lb   = w * CHUNK;

    const float Aneg = -__expf(A_log[d * D_STATE + n]);
    const float Dd   = Dv[d];

    __shared__ float sLog[NCHUNK][64];
    __shared__ float sP[NCHUNK][64];
    __shared__ float sH[NCHUNK][64];
    __shared__ float s_y[L_SEQ][4];     // 32 KB

    // ---- Phase A: chunk log-decay sum (fully parallel per t) ----
    const float clipLog = -13.815511f;   // logf(1e-6f)
    float s = 0.f;
#pragma unroll 8
    for (int t = 0; t < CHUNK; t++) {
        float dlt = delta[(size_t)(lb + t) * D_INNER + d];
        s += fmaxf(dlt * Aneg, clipLog);
    }
    sLog[w][lane] = s;
    sP[w][lane]   = __expf(s);
    __syncthreads();

    // chunk-start cA = exp(sum of previous chunks' log sums)
    float lsum = 0.f;
    for (int v = 0; v < w; v++) lsum += sLog[v][lane];
    const float cAs = __expf(lsum);

    // ---- Phase B: local accumulation c_w with known cA_start ----
    float hloc = 0.f, cA = cAs;
#pragma unroll 4
    for (int t = 0; t < CHUNK; t++) {
        size_t row = (size_t)(lb + t);
        float dlt = delta[row * D_INNER + d];
        float xv  = xpc[row * D_INNER + d];
        float bv  = Bc[row * D_STATE + n];
        float dA  = fmaxf(__expf(dlt * Aneg), 1e-6f);
        float g   = cA * __builtin_amdgcn_rcpf(cA + 1e-8f);
        hloc = dA * hloc + (dA * g) * (dlt * bv * xv);
        cA *= dA;
    }
    sH[w][lane] = hloc;
    __syncthreads();

    // chunk-start h: serial combine over previous chunk summaries
    float h = 0.f;
    for (int v = 0; v < w; v++) h = sP[v][lane] * h + sH[v][lane];

    // ---- Phase C: full recurrence + output ----
    cA = cAs;
#pragma unroll 4
    for (int t = 0; t < CHUNK; t++) {
        size_t row = (size_t)(lb + t);
        float dlt = delta[row * D_INNER + d];
        float xv  = xpc[row * D_INNER + d];
        float bv  = Bc[row * D_STATE + n];
        float cv  = Cc[row * D_STATE + n];
        float dA  = fmaxf(__expf(dlt * Aneg), 1e-6f);
        float g   = cA * __builtin_amdgcn_rcpf(cA + 1e-8f);
        h  = dA * h + (dA * g) * (dlt * bv * xv);
        cA *= dA;
        float p = h * cv;
        p += __shfl_xor(p, 1);
        p += __shfl_xor(p, 2);
        p += __shfl_xor(p, 4);
        p += __shfl_xor(p, 8);
        if (n == 0) {
            float zv = xz[row * 2048 + 1024 + d];
            float sz = zv * __builtin_amdgcn_rcpf(1.f + __expf(-zv));
            s_y[lb + t][dl] = (p + xv * Dd) * sz;
        }
    }
    __syncthreads();

    // block-wide writeout (all delta reads are done; aliasing is safe)
    for (int l = tid; l < L_SEQ; l += 1024) {
        *(float4*)(outpre + (size_t)l * D_INNER + d0) = *(const float4*)&s_y[l][0];
    }
}

// ---------------------------------------------------------------------------
extern "C" void kernel_launch(void* const* d_in, const int* in_sizes, int n_in,
                              void* d_out, int out_size, void* d_ws, size_t ws_size,
                              hipStream_t stream) {
    const float* x          = (const float*)d_in[0];
    const float* in_proj_w  = (const float*)d_in[1];
    const float* conv_w     = (const float*)d_in[2];
    const float* conv_b     = (const float*)d_in[3];
    const float* x_proj_w   = (const float*)d_in[4];
    const float* dt_proj_w  = (const float*)d_in[5];
    const float* dt_proj_b  = (const float*)d_in[6];
    const float* A_log      = (const float*)d_in[7];
    const float* Dv         = (const float*)d_in[8];
    const float* out_proj_w = (const float*)d_in[9];
    float* out = (float*)d_out;
    float* ws  = (float*)d_ws;

    // workspace layout (floats):
    float* xz    = ws;                 // [2048][2048]  xp | z
    float* xpc   = ws + 4194304;       // [2048][1024]
    float* delta = ws + 6291456;       // [2048][1024]  (reused as out_pre)
    float* Bcol  = ws + 8388608;       // [2048][16]
    float* Ccol  = ws + 8421376;       // [2048][16]

    // 1. in_proj: xz = x @ in_proj_w^T   (M=2048, N=2048, K=512)
    gemm_nt<128, 128, 16, 8, 8><<<dim3(2048 / 128, 2048 / 128), 256, 0, stream>>>(
        x, in_proj_w, xz, L_SEQ, 2 * D_INNER, D_MODEL, 2 * D_INNER);

    // 2. depthwise causal conv + silu
    conv_silu_kernel<<<L_SEQ, 256, 0, stream>>>(xz, conv_w, conv_b, xpc);

    // 3. x_proj + dt_proj + softplus
    xdbl_delta_kernel<<<L_SEQ, 256, 0, stream>>>(xpc, x_proj_w, dt_proj_w, dt_proj_b,
                                                 delta, Bcol, Ccol);

    // 4. chunked selective scan (+ D skip, * silu(z)); out_pre aliases delta
    scan_kernel<<<D_INNER / 4, 1024, 0, stream>>>(delta, xpc, xz, Bcol, Ccol,
                                                  A_log, Dv, delta);

    // 5. out_proj: out = out_pre @ out_proj_w^T  (M=2048, N=512, K=1024)
    gemm_nt<64, 64, 32, 4, 4><<<dim3(512 / 64, 2048 / 64), 256, 0, stream>>>(
        delta, out_proj_w, out, L_SEQ, D_MODEL, D_INNER, D_MODEL);
}

// Round 3
// 273.437 us; speedup vs baseline: 3.2343x; 1.2828x over previous
//
#include <hip/hip_runtime.h>
#include <hip/hip_bf16.h>

// Problem constants (B=1)
#define L_SEQ   2048
#define D_MODEL 512
#define D_INNER 1024
#define D_STATE 16
#define DT_RANK 32

typedef unsigned short u16;
typedef short bf16x8 __attribute__((ext_vector_type(8)));
typedef float f32x4  __attribute__((ext_vector_type(4)));
typedef unsigned short u16x8 __attribute__((ext_vector_type(8)));

__device__ __forceinline__ u16 f2bf(float f) {
    union { float f; unsigned u; } x; x.f = f;
    unsigned r = x.u + 0x7FFFu + ((x.u >> 16) & 1u);
    return (u16)(r >> 16);
}

__device__ __forceinline__ void gload_lds16(const void* g, void* l) {
    __builtin_amdgcn_global_load_lds((const __attribute__((address_space(1))) void*)g,
                                     (__attribute__((address_space(3))) void*)l, 16, 0, 0);
}

// ---------------------------------------------------------------------------
// bf16 MFMA GEMM (NT):  C[m][n] = sum_k A[m*K+k]*B[n*K+k], C f32.
// 256 thr = 4 waves (2x2), BK=64, single LDS buffer, global_load_lds staging.
// LDS tiles [R][64] bf16 (row = 128 B) with 16B-block XOR swizzle
// (slot = kb ^ (row&7)) applied on BOTH the global source address and the
// ds_read address (linear LDS dest per rule: gload_lds writes base+lane*16).
// ---------------------------------------------------------------------------
template<int BM, int BN>
__global__ __launch_bounds__(256)
void gemm_mfma_nt(const u16* __restrict__ A, const u16* __restrict__ B,
                  float* __restrict__ C, int M, int N, int K, int ldc) {
    constexpr int FM = BM / 32;     // 16x16 frags per wave in M
    constexpr int FN = BN / 32;
    __shared__ u16 lA[BM * 64];
    __shared__ u16 lB[BN * 64];

    const int tid  = threadIdx.x;
    const int lane = tid & 63;
    const int w    = tid >> 6;
    const int wr   = w >> 1, wc = w & 1;
    const int m0 = blockIdx.y * BM;
    const int n0 = blockIdx.x * BN;

    f32x4 acc[FM][FN];
#pragma unroll
    for (int m = 0; m < FM; m++)
#pragma unroll
        for (int n = 0; n < FN; n++) acc[m][n] = (f32x4){0.f, 0.f, 0.f, 0.f};

    // ds_read byte offsets (swizzled), constant over the K-loop
    int offA[FM][2], offB[FN][2];
#pragma unroll
    for (int m = 0; m < FM; m++) {
        int r = wr * (BM / 2) + m * 16 + (lane & 15);
#pragma unroll
        for (int s = 0; s < 2; s++) {
            int kb = s * 4 + (lane >> 4);
            offA[m][s] = r * 128 + ((kb ^ (r & 7)) << 4);
        }
    }
#pragma unroll
    for (int n = 0; n < FN; n++) {
        int r = wc * (BN / 2) + n * 16 + (lane & 15);
#pragma unroll
        for (int s = 0; s < 2; s++) {
            int kb = s * 4 + (lane >> 4);
            offB[n][s] = r * 128 + ((kb ^ (r & 7)) << 4);
        }
    }

    const int ldsbase = (tid & 192) * 16;    // wave-uniform byte base within issue

    for (int k0 = 0; k0 < K; k0 += 64) {
        __syncthreads();
#pragma unroll
        for (int i = 0; i < BM / 32; i++) {
            int o = i * 4096 + tid * 16;
            int r = o >> 7;
            int kb = ((o >> 4) & 7) ^ (r & 7);   // inverse-swizzled source block
            gload_lds16(A + (size_t)(m0 + r) * K + k0 + kb * 8,
                        (char*)lA + i * 4096 + ldsbase);
        }
#pragma unroll
        for (int i = 0; i < BN / 32; i++) {
            int o = i * 4096 + tid * 16;
            int r = o >> 7;
            int kb = ((o >> 4) & 7) ^ (r & 7);
            gload_lds16(B + (size_t)(n0 + r) * K + k0 + kb * 8,
                        (char*)lB + i * 4096 + ldsbase);
        }
        __syncthreads();   // compiler drains vmcnt before barrier

#pragma unroll
        for (int s = 0; s < 2; s++) {
            bf16x8 av[FM], bv[FN];
#pragma unroll
            for (int m = 0; m < FM; m++)
                av[m] = *(const bf16x8*)((const char*)lA + offA[m][s]);
#pragma unroll
            for (int n = 0; n < FN; n++)
                bv[n] = *(const bf16x8*)((const char*)lB + offB[n][s]);
#pragma unroll
            for (int m = 0; m < FM; m++)
#pragma unroll
                for (int n = 0; n < FN; n++)
                    acc[m][n] = __builtin_amdgcn_mfma_f32_16x16x32_bf16(
                        av[m], bv[n], acc[m][n], 0, 0, 0);
        }
    }

    // epilogue: C/D layout col=lane&15, row=(lane>>4)*4+j  (m89-verified)
    const int rb = (lane >> 4) * 4;
    const int cb = lane & 15;
#pragma unroll
    for (int m = 0; m < FM; m++)
#pragma unroll
        for (int n = 0; n < FN; n++) {
            int col = n0 + wc * (BN / 2) + n * 16 + cb;
#pragma unroll
            for (int j = 0; j < 4; j++) {
                int row = m0 + wr * (BM / 2) + m * 16 + rb + j;
                C[(size_t)row * ldc + col] = acc[m][n][j];
            }
        }
}

// ---------------------------------------------------------------------------
// Fused f32->bf16 cast of x (1M), in_proj_w (1M), out_proj_w (0.5M elems).
// One thread per 8 elements; 327680 groups total.
// ---------------------------------------------------------------------------
__global__ __launch_bounds__(256)
void cast3_kernel(const float* __restrict__ x, const float* __restrict__ w1,
                  const float* __restrict__ w2,
                  u16* __restrict__ xb, u16* __restrict__ w1b, u16* __restrict__ w2b) {
    int g = blockIdx.x * 256 + threadIdx.x;
    const float* src; u16* dst; int off;
    if (g < 131072)      { src = x;  dst = xb;  off = g; }
    else if (g < 262144) { src = w1; dst = w1b; off = g - 131072; }
    else                 { src = w2; dst = w2b; off = g - 262144; }
    float4 v0 = ((const float4*)src)[off * 2];
    float4 v1 = ((const float4*)src)[off * 2 + 1];
    u16x8 r;
    r[0] = f2bf(v0.x); r[1] = f2bf(v0.y); r[2] = f2bf(v0.z); r[3] = f2bf(v0.w);
    r[4] = f2bf(v1.x); r[5] = f2bf(v1.y); r[6] = f2bf(v1.z); r[7] = f2bf(v1.w);
    *(u16x8*)(dst + (size_t)off * 8) = r;
}

// ---------------------------------------------------------------------------
// Causal depthwise conv (4 taps) + SiLU.  xp lives in xz[:, 0:1024].
// ---------------------------------------------------------------------------
__global__ __launch_bounds__(256)
void conv_silu_kernel(const float* __restrict__ xz,
                      const float* __restrict__ w,   // [1024][4]
                      const float* __restrict__ b,   // [1024]
                      float* __restrict__ xpc) {
    int gid = blockIdx.x * 256 + threadIdx.x;
    int l  = gid >> 8;
    int dq = gid & 255;
    int d  = dq * 4;

    float4 w0 = ((const float4*)w)[d + 0];
    float4 w1 = ((const float4*)w)[d + 1];
    float4 w2 = ((const float4*)w)[d + 2];
    float4 w3 = ((const float4*)w)[d + 3];
    float4 bv = ((const float4*)b)[dq];

    float4 zf = make_float4(0.f, 0.f, 0.f, 0.f);
    float4 x0 = (l >= 3) ? *(const float4*)(xz + (size_t)(l - 3) * 2048 + d) : zf;
    float4 x1 = (l >= 2) ? *(const float4*)(xz + (size_t)(l - 2) * 2048 + d) : zf;
    float4 x2 = (l >= 1) ? *(const float4*)(xz + (size_t)(l - 1) * 2048 + d) : zf;
    float4 x3 =            *(const float4*)(xz + (size_t)(l    ) * 2048 + d);

    float4 r;
    r.x = bv.x + x0.x * w0.x + x1.x * w0.y + x2.x * w0.z + x3.x * w0.w;
    r.y = bv.y + x0.y * w1.x + x1.y * w1.y + x2.y * w1.z + x3.y * w1.w;
    r.z = bv.z + x0.z * w2.x + x1.z * w2.y + x2.z * w2.z + x3.z * w2.w;
    r.w = bv.w + x0.w * w3.x + x1.w * w3.y + x2.w * w3.z + x3.w * w3.w;

    r.x = r.x / (1.f + expf(-r.x));
    r.y = r.y / (1.f + expf(-r.y));
    r.z = r.z / (1.f + expf(-r.z));
    r.w = r.w / (1.f + expf(-r.w));

    *(float4*)(xpc + (size_t)l * 1024 + d) = r;
}

// ---------------------------------------------------------------------------
// Fused x_proj + dt_proj + softplus.  One block (256 thr) per sequence pos l.
// ---------------------------------------------------------------------------
__global__ __launch_bounds__(256)
void xdbl_delta_kernel(const float* __restrict__ xpc,
                       const float* __restrict__ xw,   // x_proj_w [64][1024]
                       const float* __restrict__ dtw,  // dt_proj_w [1024][32]
                       const float* __restrict__ dtb,  // dt_proj_b [1024]
                       float* __restrict__ delta,
                       float* __restrict__ Bc, float* __restrict__ Cc) {
    const int l = blockIdx.x;
    const int tid = threadIdx.x;
    __shared__ float sx[1024];
    __shared__ float sred[4][64];
    __shared__ float sdbl[64];

    ((float4*)sx)[tid] = ((const float4*)(xpc + (size_t)l * 1024))[tid];
    __syncthreads();

    {
        int e = tid & 63, part = tid >> 6;
        const float* wrow = xw + (size_t)e * 1024 + part * 256;
        const float* xrow = sx + part * 256;
        float s = 0.f;
#pragma unroll 8
        for (int k = 0; k < 256; k += 4) {
            float4 wv = *(const float4*)(wrow + k);
            s += wv.x * xrow[k] + wv.y * xrow[k + 1] + wv.z * xrow[k + 2] + wv.w * xrow[k + 3];
        }
        sred[part][e] = s;
    }
    __syncthreads();
    if (tid < 64) {
        float v = sred[0][tid] + sred[1][tid] + sred[2][tid] + sred[3][tid];
        sdbl[tid] = v;
        if (tid >= 32 && tid < 48) Bc[(size_t)l * 16 + (tid - 32)] = v;
        if (tid >= 48)             Cc[(size_t)l * 16 + (tid - 48)] = v;
    }
    __syncthreads();

#pragma unroll
    for (int q = 0; q < 4; q++) {
        int d = tid + q * 256;
        float a = dtb[d];
        const float* wr = dtw + (size_t)d * 32;
#pragma unroll
        for (int r = 0; r < 32; r += 4) {
            float4 wv = *(const float4*)(wr + r);
            a += wv.x * sdbl[r] + wv.y * sdbl[r + 1] + wv.z * sdbl[r + 2] + wv.w * sdbl[r + 3];
        }
        float sp = fmaxf(a, 0.f) + log1pf(expf(-fabsf(a)));
        delta[(size_t)l * 1024 + d] = sp;
    }
}

// ---------------------------------------------------------------------------
// Chunked selective scan (3-phase).  Same math as round 2 (verified), but
// writes out_pre as bf16 for the MFMA out-proj.
// ---------------------------------------------------------------------------
#define CHUNK 128
#define NCHUNK 16

__global__ __launch_bounds__(1024)
void scan_kernel(const float* __restrict__ delta,
                 const float* __restrict__ xpc,
                 const float* __restrict__ xz,    // z at cols [1024,2048)
                 const float* __restrict__ Bc, const float* __restrict__ Cc,
                 const float* __restrict__ A_log, const float* __restrict__ Dv,
                 u16* __restrict__ ypre) {
    const int tid  = threadIdx.x;
    const int w    = tid >> 6;
    const int lane = tid & 63;
    const int dl   = lane >> 4;
    const int n    = lane & 15;
    const int d0   = blockIdx.x * 4;
    const int d    = d0 + dl;
    const int lb   = w * CHUNK;

    const float Aneg = -__expf(A_log[d * D_STATE + n]);
    const float Dd   = Dv[d];

    __shared__ float sLog[NCHUNK][64];
    __shared__ float sP[NCHUNK][64];
    __shared__ float sH[NCHUNK][64];
    __shared__ float s_y[L_SEQ][4];

    // ---- Phase A: chunk log-decay sum ----
    const float clipLog = -13.815511f;   // logf(1e-6f)
    float s = 0.f;
#pragma unroll 8
    for (int t = 0; t < CHUNK; t++) {
        float dlt = delta[(size_t)(lb + t) * D_INNER + d];
        s += fmaxf(dlt * Aneg, clipLog);
    }
    sLog[w][lane] = s;
    sP[w][lane]   = __expf(s);
    __syncthreads();

    float lsum = 0.f;
    for (int v = 0; v < w; v++) lsum += sLog[v][lane];
    const float cAs = __expf(lsum);

    // ---- Phase B: local accumulation with known cA_start ----
    float hloc = 0.f, cA = cAs;
#pragma unroll 4
    for (int t = 0; t < CHUNK; t++) {
        size_t row = (size_t)(lb + t);
        float dlt = delta[row * D_INNER + d];
        float xv  = xpc[row * D_INNER + d];
        float bv  = Bc[row * D_STATE + n];
        float dA  = fmaxf(__expf(dlt * Aneg), 1e-6f);
        float g   = cA * __builtin_amdgcn_rcpf(cA + 1e-8f);
        hloc = dA * hloc + (dA * g) * (dlt * bv * xv);
        cA *= dA;
    }
    sH[w][lane] = hloc;
    __syncthreads();

    float h = 0.f;
    for (int v = 0; v < w; v++) h = sP[v][lane] * h + sH[v][lane];

    // ---- Phase C: full recurrence + output ----
    cA = cAs;
#pragma unroll 4
    for (int t = 0; t < CHUNK; t++) {
        size_t row = (size_t)(lb + t);
        float dlt = delta[row * D_INNER + d];
        float xv  = xpc[row * D_INNER + d];
        float bv  = Bc[row * D_STATE + n];
        float cv  = Cc[row * D_STATE + n];
        float dA  = fmaxf(__expf(dlt * Aneg), 1e-6f);
        float g   = cA * __builtin_amdgcn_rcpf(cA + 1e-8f);
        h  = dA * h + (dA * g) * (dlt * bv * xv);
        cA *= dA;
        float p = h * cv;
        p += __shfl_xor(p, 1);
        p += __shfl_xor(p, 2);
        p += __shfl_xor(p, 4);
        p += __shfl_xor(p, 8);
        if (n == 0) {
            float zv = xz[row * 2048 + 1024 + d];
            float sz = zv * __builtin_amdgcn_rcpf(1.f + __expf(-zv));
            s_y[lb + t][dl] = (p + xv * Dd) * sz;
        }
    }
    __syncthreads();

    for (int l = tid; l < L_SEQ; l += 1024) {
        float4 v = *(const float4*)&s_y[l][0];
        ushort4 o;
        o.x = f2bf(v.x); o.y = f2bf(v.y); o.z = f2bf(v.z); o.w = f2bf(v.w);
        *(ushort4*)(ypre + (size_t)l * D_INNER + d0) = o;
    }
}

// ---------------------------------------------------------------------------
extern "C" void kernel_launch(void* const* d_in, const int* in_sizes, int n_in,
                              void* d_out, int out_size, void* d_ws, size_t ws_size,
                              hipStream_t stream) {
    const float* x          = (const float*)d_in[0];
    const float* in_proj_w  = (const float*)d_in[1];
    const float* conv_w     = (const float*)d_in[2];
    const float* conv_b     = (const float*)d_in[3];
    const float* x_proj_w   = (const float*)d_in[4];
    const float* dt_proj_w  = (const float*)d_in[5];
    const float* dt_proj_b  = (const float*)d_in[6];
    const float* A_log      = (const float*)d_in[7];
    const float* Dv         = (const float*)d_in[8];
    const float* out_proj_w = (const float*)d_in[9];
    float* out = (float*)d_out;
    float* ws  = (float*)d_ws;

    // workspace layout (float offsets):
    float* xz    = ws;                 // [2048][2048] f32  xp | z
    float* xpc   = ws + 4194304;       // [2048][1024] f32
    float* delta = ws + 6291456;       // [2048][1024] f32
    float* Bcol  = ws + 8388608;       // [2048][16]
    float* Ccol  = ws + 8421376;       // [2048][16]
    u16*   xb    = (u16*)(ws + 8454144);   // [2048][512]  bf16
    u16*   w1b   = (u16*)(ws + 8978432);   // [2048][512]  bf16
    u16*   w2b   = (u16*)(ws + 9502720);   // [512][1024]  bf16
    u16*   ypre  = (u16*)(ws + 9764864);   // [2048][1024] bf16

    // 0. cast x, in_proj_w, out_proj_w to bf16
    cast3_kernel<<<1280, 256, 0, stream>>>(x, in_proj_w, out_proj_w, xb, w1b, w2b);

    // 1. in_proj (bf16 MFMA): xz = x @ in_proj_w^T  (M=2048,N=2048,K=512)
    gemm_mfma_nt<128, 128><<<dim3(2048 / 128, 2048 / 128), 256, 0, stream>>>(
        xb, w1b, xz, L_SEQ, 2 * D_INNER, D_MODEL, 2 * D_INNER);

    // 2. depthwise causal conv + silu
    conv_silu_kernel<<<L_SEQ, 256, 0, stream>>>(xz, conv_w, conv_b, xpc);

    // 3. x_proj + dt_proj + softplus
    xdbl_delta_kernel<<<L_SEQ, 256, 0, stream>>>(xpc, x_proj_w, dt_proj_w, dt_proj_b,
                                                 delta, Bcol, Ccol);

    // 4. chunked selective scan (+ D skip, * silu(z)) -> bf16 out_pre
    scan_kernel<<<D_INNER / 4, 1024, 0, stream>>>(delta, xpc, xz, Bcol, Ccol,
                                                  A_log, Dv, ypre);

    // 5. out_proj (bf16 MFMA): out = out_pre @ out_proj_w^T (M=2048,N=512,K=1024)
    gemm_mfma_nt<64, 64><<<dim3(512 / 64, 2048 / 64), 256, 0, stream>>>(
        ypre, w2b, out, L_SEQ, D_MODEL, D_INNER, D_MODEL);
}

// Round 4
// 199.272 us; speedup vs baseline: 4.4380x; 1.3722x over previous
//
#include <hip/hip_runtime.h>
#include <hip/hip_bf16.h>

// Problem constants (B=1)
#define L_SEQ   2048
#define D_MODEL 512
#define D_INNER 1024
#define D_STATE 16
#define DT_RANK 32

typedef unsigned short u16;
typedef short bf16x8 __attribute__((ext_vector_type(8)));
typedef float f32x4  __attribute__((ext_vector_type(4)));
typedef unsigned short u16x8 __attribute__((ext_vector_type(8)));

__device__ __forceinline__ u16 f2bf(float f) {
    union { float f; unsigned u; } x; x.f = f;
    unsigned r = x.u + 0x7FFFu + ((x.u >> 16) & 1u);
    return (u16)(r >> 16);
}

__device__ __forceinline__ void gload_lds16(const void* g, void* l) {
    __builtin_amdgcn_global_load_lds((const __attribute__((address_space(1))) void*)g,
                                     (__attribute__((address_space(3))) void*)l, 16, 0, 0);
}

// ---------------------------------------------------------------------------
// bf16 MFMA GEMM (NT):  C[m][n] = sum_k A[m*K+k]*B[n*K+k], C f32.  (unchanged)
// ---------------------------------------------------------------------------
template<int BM, int BN>
__global__ __launch_bounds__(256)
void gemm_mfma_nt(const u16* __restrict__ A, const u16* __restrict__ B,
                  float* __restrict__ C, int M, int N, int K, int ldc) {
    constexpr int FM = BM / 32;
    constexpr int FN = BN / 32;
    __shared__ u16 lA[BM * 64];
    __shared__ u16 lB[BN * 64];

    const int tid  = threadIdx.x;
    const int lane = tid & 63;
    const int w    = tid >> 6;
    const int wr   = w >> 1, wc = w & 1;
    const int m0 = blockIdx.y * BM;
    const int n0 = blockIdx.x * BN;

    f32x4 acc[FM][FN];
#pragma unroll
    for (int m = 0; m < FM; m++)
#pragma unroll
        for (int n = 0; n < FN; n++) acc[m][n] = (f32x4){0.f, 0.f, 0.f, 0.f};

    int offA[FM][2], offB[FN][2];
#pragma unroll
    for (int m = 0; m < FM; m++) {
        int r = wr * (BM / 2) + m * 16 + (lane & 15);
#pragma unroll
        for (int s = 0; s < 2; s++) {
            int kb = s * 4 + (lane >> 4);
            offA[m][s] = r * 128 + ((kb ^ (r & 7)) << 4);
        }
    }
#pragma unroll
    for (int n = 0; n < FN; n++) {
        int r = wc * (BN / 2) + n * 16 + (lane & 15);
#pragma unroll
        for (int s = 0; s < 2; s++) {
            int kb = s * 4 + (lane >> 4);
            offB[n][s] = r * 128 + ((kb ^ (r & 7)) << 4);
        }
    }

    const int ldsbase = (tid & 192) * 16;

    for (int k0 = 0; k0 < K; k0 += 64) {
        __syncthreads();
#pragma unroll
        for (int i = 0; i < BM / 32; i++) {
            int o = i * 4096 + tid * 16;
            int r = o >> 7;
            int kb = ((o >> 4) & 7) ^ (r & 7);
            gload_lds16(A + (size_t)(m0 + r) * K + k0 + kb * 8,
                        (char*)lA + i * 4096 + ldsbase);
        }
#pragma unroll
        for (int i = 0; i < BN / 32; i++) {
            int o = i * 4096 + tid * 16;
            int r = o >> 7;
            int kb = ((o >> 4) & 7) ^ (r & 7);
            gload_lds16(B + (size_t)(n0 + r) * K + k0 + kb * 8,
                        (char*)lB + i * 4096 + ldsbase);
        }
        __syncthreads();

#pragma unroll
        for (int s = 0; s < 2; s++) {
            bf16x8 av[FM], bv[FN];
#pragma unroll
            for (int m = 0; m < FM; m++)
                av[m] = *(const bf16x8*)((const char*)lA + offA[m][s]);
#pragma unroll
            for (int n = 0; n < FN; n++)
                bv[n] = *(const bf16x8*)((const char*)lB + offB[n][s]);
#pragma unroll
            for (int m = 0; m < FM; m++)
#pragma unroll
                for (int n = 0; n < FN; n++)
                    acc[m][n] = __builtin_amdgcn_mfma_f32_16x16x32_bf16(
                        av[m], bv[n], acc[m][n], 0, 0, 0);
        }
    }

    const int rb = (lane >> 4) * 4;
    const int cb = lane & 15;
#pragma unroll
    for (int m = 0; m < FM; m++)
#pragma unroll
        for (int n = 0; n < FN; n++) {
            int col = n0 + wc * (BN / 2) + n * 16 + cb;
#pragma unroll
            for (int j = 0; j < 4; j++) {
                int row = m0 + wr * (BM / 2) + m * 16 + rb + j;
                C[(size_t)row * ldc + col] = acc[m][n][j];
            }
        }
}

// ---------------------------------------------------------------------------
// Fused f32->bf16 cast of x, in_proj_w, out_proj_w.  (unchanged)
// ---------------------------------------------------------------------------
__global__ __launch_bounds__(256)
void cast3_kernel(const float* __restrict__ x, const float* __restrict__ w1,
                  const float* __restrict__ w2,
                  u16* __restrict__ xb, u16* __restrict__ w1b, u16* __restrict__ w2b) {
    int g = blockIdx.x * 256 + threadIdx.x;
    const float* src; u16* dst; int off;
    if (g < 131072)      { src = x;  dst = xb;  off = g; }
    else if (g < 262144) { src = w1; dst = w1b; off = g - 131072; }
    else                 { src = w2; dst = w2b; off = g - 262144; }
    float4 v0 = ((const float4*)src)[off * 2];
    float4 v1 = ((const float4*)src)[off * 2 + 1];
    u16x8 r;
    r[0] = f2bf(v0.x); r[1] = f2bf(v0.y); r[2] = f2bf(v0.z); r[3] = f2bf(v0.w);
    r[4] = f2bf(v1.x); r[5] = f2bf(v1.y); r[6] = f2bf(v1.z); r[7] = f2bf(v1.w);
    *(u16x8*)(dst + (size_t)off * 8) = r;
}

// ---------------------------------------------------------------------------
// Causal depthwise conv (4 taps) + SiLU, with transposed outputs.
// 64l x 64d tile per block.  Writes:
//   xpc[l][d]   (row layout, feeds x_proj)
//   xpcT[d][l]  (feeds scan, coalesced along l)
//   gzT[d][l] = silu(z[l][d])  (feeds scan gating)
// ---------------------------------------------------------------------------
__global__ __launch_bounds__(256)
void conv_tr_kernel(const float* __restrict__ xz,
                    const float* __restrict__ w,   // [1024][4]
                    const float* __restrict__ b,   // [1024]
                    float* __restrict__ xpc,
                    float* __restrict__ xpcT,
                    float* __restrict__ gzT) {
    const int tid = threadIdx.x;
    const int d0 = blockIdx.x * 64;
    const int l0 = blockIdx.y * 64;

    __shared__ float txp[67][65];
    __shared__ float trb[64][65];

    // stage xp tile rows l0-3 .. l0+63
    {
        int rr = tid >> 4;            // 0..15
        int c4 = (tid & 15) * 4;
        for (int r = rr; r < 67; r += 16) {
            int l = l0 - 3 + r;
            float4 v = (l >= 0) ? *(const float4*)(xz + (size_t)l * 2048 + d0 + c4)
                                : make_float4(0.f, 0.f, 0.f, 0.f);
            txp[r][c4] = v.x; txp[r][c4 + 1] = v.y;
            txp[r][c4 + 2] = v.z; txp[r][c4 + 3] = v.w;
        }
    }
    __syncthreads();

    const int dd = tid & 63;
    const int lq = tid >> 6;          // 0..3
    const int d  = d0 + dd;
    const float4 wv = ((const float4*)w)[d];
    const float bias = b[d];

    {
        float x0 = txp[lq * 16 + 0][dd];
        float x1 = txp[lq * 16 + 1][dd];
        float x2 = txp[lq * 16 + 2][dd];
#pragma unroll
        for (int i = 0; i < 16; i++) {
            int ll = lq * 16 + i;
            float x3 = txp[ll + 3][dd];
            float r = bias + x0 * wv.x + x1 * wv.y + x2 * wv.z + x3 * wv.w;
            r = r / (1.f + __expf(-r));
            xpc[(size_t)(l0 + ll) * 1024 + d] = r;   // coalesced across dd
            trb[dd][ll] = r;
            x0 = x1; x1 = x2; x2 = x3;
        }
    }
    __syncthreads();

    // write xpcT rows (coalesced along l)
    {
        int dd2 = tid >> 2;
        int lc  = (tid & 3) * 16;
#pragma unroll
        for (int m = 0; m < 16; m += 4) {
            float4 v = make_float4(trb[dd2][lc + m], trb[dd2][lc + m + 1],
                                   trb[dd2][lc + m + 2], trb[dd2][lc + m + 3]);
            *(float4*)(xpcT + (size_t)(d0 + dd2) * 2048 + l0 + lc + m) = v;
        }
    }
    __syncthreads();

    // silu(z) transpose
#pragma unroll
    for (int i = 0; i < 16; i++) {
        int ll = lq * 16 + i;
        float zv = xz[(size_t)(l0 + ll) * 2048 + 1024 + d];
        trb[dd][ll] = zv / (1.f + __expf(-zv));
    }
    __syncthreads();
    {
        int dd2 = tid >> 2;
        int lc  = (tid & 3) * 16;
#pragma unroll
        for (int m = 0; m < 16; m += 4) {
            float4 v = make_float4(trb[dd2][lc + m], trb[dd2][lc + m + 1],
                                   trb[dd2][lc + m + 2], trb[dd2][lc + m + 3]);
            *(float4*)(gzT + (size_t)(d0 + dd2) * 2048 + l0 + lc + m) = v;
        }
    }
}

// ---------------------------------------------------------------------------
// x_proj only: x_dblT[e][l] = dot(xpc[l][:], xw[e][:]).  Block per l.
// Rows 0..31 feed delta; rows 32..47 = B_T; rows 48..63 = C_T.
// ---------------------------------------------------------------------------
__global__ __launch_bounds__(256)
void xproj_kernel(const float* __restrict__ xpc,
                  const float* __restrict__ xw,   // [64][1024]
                  float* __restrict__ xdblT) {    // [64][2048]
    const int l = blockIdx.x;
    const int tid = threadIdx.x;
    __shared__ float sx[1024];
    __shared__ float sred[4][64];

    ((float4*)sx)[tid] = ((const float4*)(xpc + (size_t)l * 1024))[tid];
    __syncthreads();

    int e = tid & 63, part = tid >> 6;
    const float* wrow = xw + (size_t)e * 1024 + part * 256;
    const float* xrow = sx + part * 256;
    float s = 0.f;
#pragma unroll 8
    for (int k = 0; k < 256; k += 4) {
        float4 wv = *(const float4*)(wrow + k);
        s += wv.x * xrow[k] + wv.y * xrow[k + 1] + wv.z * xrow[k + 2] + wv.w * xrow[k + 3];
    }
    sred[part][e] = s;
    __syncthreads();
    if (tid < 64) {
        float v = sred[0][tid] + sred[1][tid] + sred[2][tid] + sred[3][tid];
        xdblT[(size_t)tid * 2048 + l] = v;
    }
}

// ---------------------------------------------------------------------------
// dt_proj + softplus, transposed output:
//   deltaT[d][l] = softplus(dtb[d] + sum_r dtw[d][r] * xdblT[r][l])
// Block: 64 d x 128 l; LDS-staged xdblT tile, conflict-free interleave.
// ---------------------------------------------------------------------------
__global__ __launch_bounds__(256)
void deltaT_kernel(const float* __restrict__ xdblT,
                   const float* __restrict__ dtw,   // [1024][32]
                   const float* __restrict__ dtb,
                   float* __restrict__ deltaT) {    // [1024][2048]
    const int tid = threadIdx.x;
    const int d0 = blockIdx.x * 64;
    const int l0 = blockIdx.y * 128;

    __shared__ float sx[32][128];
#pragma unroll
    for (int it = 0; it < 4; it++) {
        int idx = it * 256 + tid;
        int r  = idx >> 5;
        int c4 = (idx & 31) * 4;
        *(float4*)&sx[r][c4] = *(const float4*)(xdblT + (size_t)r * 2048 + l0 + c4);
    }

    const int dl = tid >> 2;
    const int lg = tid & 3;
    const int d  = d0 + dl;
    float wreg[32];
#pragma unroll
    for (int r4 = 0; r4 < 32; r4 += 4)
        *(float4*)&wreg[r4] = *(const float4*)(dtw + (size_t)d * 32 + r4);
    const float bias = dtb[d];
    __syncthreads();

#pragma unroll
    for (int j = 0; j < 8; j++) {
        float4 a = make_float4(bias, bias, bias, bias);
        const int col = j * 16 + lg * 4;
#pragma unroll
        for (int r = 0; r < 32; r++) {
            float4 v = *(const float4*)&sx[r][col];
            a.x = fmaf(wreg[r], v.x, a.x);
            a.y = fmaf(wreg[r], v.y, a.y);
            a.z = fmaf(wreg[r], v.z, a.z);
            a.w = fmaf(wreg[r], v.w, a.w);
        }
        float4 o;
        o.x = fmaxf(a.x, 0.f) + log1pf(expf(-fabsf(a.x)));
        o.y = fmaxf(a.y, 0.f) + log1pf(expf(-fabsf(a.y)));
        o.z = fmaxf(a.z, 0.f) + log1pf(expf(-fabsf(a.z)));
        o.w = fmaxf(a.w, 0.f) + log1pf(expf(-fabsf(a.w)));
        *(float4*)(deltaT + (size_t)d * 2048 + l0 + col) = o;
    }
}

// ---------------------------------------------------------------------------
// Chunked selective scan (3-phase), all inputs in [d][l] / [n][l] layout:
// every load is a contiguous float4 along l (broadcast across lanes sharing
// the row).  Math identical to the verified round-2 kernel.
// ---------------------------------------------------------------------------
#define CHUNK 128
#define NCHUNK 16

__global__ __launch_bounds__(1024)
void scan_kernel(const float* __restrict__ deltaT,
                 const float* __restrict__ xpcT,
                 const float* __restrict__ gzT,
                 const float* __restrict__ xdblT,
                 const float* __restrict__ A_log, const float* __restrict__ Dv,
                 u16* __restrict__ ypre) {
    const int tid  = threadIdx.x;
    const int w    = tid >> 6;
    const int lane = tid & 63;
    const int dl   = lane >> 4;
    const int n    = lane & 15;
    const int d0   = blockIdx.x * 4;
    const int d    = d0 + dl;
    const int lb   = w * CHUNK;

    const float Aneg = -__expf(A_log[d * D_STATE + n]);
    const float Dd   = Dv[d];

    const f32x4* dT4 = (const f32x4*)(deltaT + (size_t)d * L_SEQ + lb);
    const f32x4* xT4 = (const f32x4*)(xpcT   + (size_t)d * L_SEQ + lb);
    const f32x4* gT4 = (const f32x4*)(gzT    + (size_t)d * L_SEQ + lb);
    const f32x4* bT4 = (const f32x4*)(xdblT + (size_t)(32 + n) * L_SEQ + lb);
    const f32x4* cT4 = (const f32x4*)(xdblT + (size_t)(48 + n) * L_SEQ + lb);

    __shared__ float sLog[NCHUNK][64];
    __shared__ float sP[NCHUNK][64];
    __shared__ float sH[NCHUNK][64];
    __shared__ float s_y[L_SEQ][4];

    // ---- Phase A: chunk log-decay sum ----
    const float clipLog = -13.815511f;   // logf(1e-6f)
    float s = 0.f;
#pragma unroll 8
    for (int i = 0; i < 32; i++) {
        f32x4 d4 = dT4[i];
#pragma unroll
        for (int k = 0; k < 4; k++) s += fmaxf(d4[k] * Aneg, clipLog);
    }
    sLog[w][lane] = s;
    sP[w][lane]   = __expf(s);
    __syncthreads();

    float lsum = 0.f;
    for (int v = 0; v < w; v++) lsum += sLog[v][lane];
    const float cAs = __expf(lsum);

    // ---- Phase B: local accumulation with known cA_start ----
    float hloc = 0.f, cA = cAs;
    for (int i = 0; i < 32; i++) {
        f32x4 d4 = dT4[i], x4 = xT4[i], b4 = bT4[i];
#pragma unroll
        for (int k = 0; k < 4; k++) {
            float dA = fmaxf(__expf(d4[k] * Aneg), 1e-6f);
            float g  = cA * __builtin_amdgcn_rcpf(cA + 1e-8f);
            hloc = dA * hloc + (dA * g) * (d4[k] * b4[k] * x4[k]);
            cA *= dA;
        }
    }
    sH[w][lane] = hloc;
    __syncthreads();

    float h = 0.f;
    for (int v = 0; v < w; v++) h = sP[v][lane] * h + sH[v][lane];

    // ---- Phase C: full recurrence + output ----
    cA = cAs;
    for (int i = 0; i < 32; i++) {
        f32x4 d4 = dT4[i], x4 = xT4[i], b4 = bT4[i], c4 = cT4[i];
        f32x4 g4 = {0.f, 0.f, 0.f, 0.f};
        if (n == 0) g4 = gT4[i];
#pragma unroll
        for (int k = 0; k < 4; k++) {
            float dA = fmaxf(__expf(d4[k] * Aneg), 1e-6f);
            float g  = cA * __builtin_amdgcn_rcpf(cA + 1e-8f);
            h  = dA * h + (dA * g) * (d4[k] * b4[k] * x4[k]);
            cA *= dA;
            float p = h * c4[k];
            p += __shfl_xor(p, 1);
            p += __shfl_xor(p, 2);
            p += __shfl_xor(p, 4);
            p += __shfl_xor(p, 8);
            if (n == 0) s_y[lb + 4 * i + k][dl] = (p + x4[k] * Dd) * g4[k];
        }
    }
    __syncthreads();

    for (int l = tid; l < L_SEQ; l += 1024) {
        float4 v = *(const float4*)&s_y[l][0];
        ushort4 o;
        o.x = f2bf(v.x); o.y = f2bf(v.y); o.z = f2bf(v.z); o.w = f2bf(v.w);
        *(ushort4*)(ypre + (size_t)l * D_INNER + d0) = o;
    }
}

// ---------------------------------------------------------------------------
extern "C" void kernel_launch(void* const* d_in, const int* in_sizes, int n_in,
                              void* d_out, int out_size, void* d_ws, size_t ws_size,
                              hipStream_t stream) {
    const float* x          = (const float*)d_in[0];
    const float* in_proj_w  = (const float*)d_in[1];
    const float* conv_w     = (const float*)d_in[2];
    const float* conv_b     = (const float*)d_in[3];
    const float* x_proj_w   = (const float*)d_in[4];
    const float* dt_proj_w  = (const float*)d_in[5];
    const float* dt_proj_b  = (const float*)d_in[6];
    const float* A_log      = (const float*)d_in[7];
    const float* Dv         = (const float*)d_in[8];
    const float* out_proj_w = (const float*)d_in[9];
    float* out = (float*)d_out;
    float* ws  = (float*)d_ws;

    // workspace layout (float offsets), with liveness-based overlays:
    //   [0 .. 4M)          xz  (dead after conv)  -> reused by ypre + xdblT
    float* xz     = ws;                        // [2048][2048] f32
    u16*   ypre   = (u16*)ws;                  // [2048][1024] bf16 (1,048,576 fl)
    float* xdblT  = ws + 1048576;              // [64][2048]   f32  (131,072 fl)
    float* xpcT   = ws + 4194304;              // [1024][2048] f32
    float* gzT    = ws + 6291456;              // [1024][2048] f32
    float* xpc    = ws + 8388608;              // [2048][1024] f32 (dead after xproj)
    float* deltaT = ws + 8388608;              // [1024][2048] f32 (overlays xpc)
    u16*   xb     = (u16*)(ws + 10485760);     // [2048][512]  bf16
    u16*   w1b    = (u16*)(ws + 11010048);     // [2048][512]  bf16
    u16*   w2b    = (u16*)(ws + 11534336);     // [512][1024]  bf16

    // 0. cast x, in_proj_w, out_proj_w to bf16
    cast3_kernel<<<1280, 256, 0, stream>>>(x, in_proj_w, out_proj_w, xb, w1b, w2b);

    // 1. in_proj (bf16 MFMA): xz = x @ in_proj_w^T  (M=2048,N=2048,K=512)
    gemm_mfma_nt<128, 128><<<dim3(2048 / 128, 2048 / 128), 256, 0, stream>>>(
        xb, w1b, xz, L_SEQ, 2 * D_INNER, D_MODEL, 2 * D_INNER);

    // 2. conv + silu, emit xpc rows + transposed xpcT / gzT
    conv_tr_kernel<<<dim3(16, 32), 256, 0, stream>>>(xz, conv_w, conv_b,
                                                     xpc, xpcT, gzT);

    // 3. x_proj -> x_dblT (rows 32..63 are B_T/C_T)
    xproj_kernel<<<L_SEQ, 256, 0, stream>>>(xpc, x_proj_w, xdblT);

    // 4. dt_proj + softplus -> deltaT (overlays dead xpc)
    deltaT_kernel<<<dim3(16, 16), 256, 0, stream>>>(xdblT, dt_proj_w, dt_proj_b,
                                                    deltaT);

    // 5. chunked selective scan (+ D skip, * silu(z)) -> bf16 ypre
    scan_kernel<<<D_INNER / 4, 1024, 0, stream>>>(deltaT, xpcT, gzT, xdblT,
                                                  A_log, Dv, ypre);

    // 6. out_proj (bf16 MFMA): out = ypre @ out_proj_w^T (M=2048,N=512,K=1024)
    gemm_mfma_nt<64, 64><<<dim3(512 / 64, 2048 / 64), 256, 0, stream>>>(
        ypre, w2b, out, L_SEQ, D_MODEL, D_INNER, D_MODEL);
}

// Round 5
// 167.789 us; speedup vs baseline: 5.2708x; 1.1876x over previous
//
#include <hip/hip_runtime.h>
#include <hip/hip_bf16.h>

// Problem constants (B=1)
#define L_SEQ   2048
#define D_MODEL 512
#define D_INNER 1024
#define D_STATE 16
#define DT_RANK 32

typedef unsigned short u16;
typedef short bf16x8 __attribute__((ext_vector_type(8)));
typedef float f32x4  __attribute__((ext_vector_type(4)));
typedef unsigned short u16x8 __attribute__((ext_vector_type(8)));

__device__ __forceinline__ u16 f2bf(float f) {
    union { float f; unsigned u; } x; x.f = f;
    unsigned r = x.u + 0x7FFFu + ((x.u >> 16) & 1u);
    return (u16)(r >> 16);
}

__device__ __forceinline__ void gload_lds16(const void* g, void* l) {
    __builtin_amdgcn_global_load_lds((const __attribute__((address_space(1))) void*)g,
                                     (__attribute__((address_space(3))) void*)l, 16, 0, 0);
}

// ---------------------------------------------------------------------------
// bf16 MFMA GEMM (NT):  C[m][n] = sum_k A[m*K+k]*B[n*K+k], C f32.  (verified)
// ---------------------------------------------------------------------------
template<int BM, int BN>
__global__ __launch_bounds__(256)
void gemm_mfma_nt(const u16* __restrict__ A, const u16* __restrict__ B,
                  float* __restrict__ C, int M, int N, int K, int ldc) {
    constexpr int FM = BM / 32;
    constexpr int FN = BN / 32;
    __shared__ u16 lA[BM * 64];
    __shared__ u16 lB[BN * 64];

    const int tid  = threadIdx.x;
    const int lane = tid & 63;
    const int w    = tid >> 6;
    const int wr   = w >> 1, wc = w & 1;
    const int m0 = blockIdx.y * BM;
    const int n0 = blockIdx.x * BN;

    f32x4 acc[FM][FN];
#pragma unroll
    for (int m = 0; m < FM; m++)
#pragma unroll
        for (int n = 0; n < FN; n++) acc[m][n] = (f32x4){0.f, 0.f, 0.f, 0.f};

    int offA[FM][2], offB[FN][2];
#pragma unroll
    for (int m = 0; m < FM; m++) {
        int r = wr * (BM / 2) + m * 16 + (lane & 15);
#pragma unroll
        for (int s = 0; s < 2; s++) {
            int kb = s * 4 + (lane >> 4);
            offA[m][s] = r * 128 + ((kb ^ (r & 7)) << 4);
        }
    }
#pragma unroll
    for (int n = 0; n < FN; n++) {
        int r = wc * (BN / 2) + n * 16 + (lane & 15);
#pragma unroll
        for (int s = 0; s < 2; s++) {
            int kb = s * 4 + (lane >> 4);
            offB[n][s] = r * 128 + ((kb ^ (r & 7)) << 4);
        }
    }

    const int ldsbase = (tid & 192) * 16;

    for (int k0 = 0; k0 < K; k0 += 64) {
        __syncthreads();
#pragma unroll
        for (int i = 0; i < BM / 32; i++) {
            int o = i * 4096 + tid * 16;
            int r = o >> 7;
            int kb = ((o >> 4) & 7) ^ (r & 7);
            gload_lds16(A + (size_t)(m0 + r) * K + k0 + kb * 8,
                        (char*)lA + i * 4096 + ldsbase);
        }
#pragma unroll
        for (int i = 0; i < BN / 32; i++) {
            int o = i * 4096 + tid * 16;
            int r = o >> 7;
            int kb = ((o >> 4) & 7) ^ (r & 7);
            gload_lds16(B + (size_t)(n0 + r) * K + k0 + kb * 8,
                        (char*)lB + i * 4096 + ldsbase);
        }
        __syncthreads();

#pragma unroll
        for (int s = 0; s < 2; s++) {
            bf16x8 av[FM], bv[FN];
#pragma unroll
            for (int m = 0; m < FM; m++)
                av[m] = *(const bf16x8*)((const char*)lA + offA[m][s]);
#pragma unroll
            for (int n = 0; n < FN; n++)
                bv[n] = *(const bf16x8*)((const char*)lB + offB[n][s]);
#pragma unroll
            for (int m = 0; m < FM; m++)
#pragma unroll
                for (int n = 0; n < FN; n++)
                    acc[m][n] = __builtin_amdgcn_mfma_f32_16x16x32_bf16(
                        av[m], bv[n], acc[m][n], 0, 0, 0);
        }
    }

    const int rb = (lane >> 4) * 4;
    const int cb = lane & 15;
#pragma unroll
    for (int m = 0; m < FM; m++)
#pragma unroll
        for (int n = 0; n < FN; n++) {
            int col = n0 + wc * (BN / 2) + n * 16 + cb;
#pragma unroll
            for (int j = 0; j < 4; j++) {
                int row = m0 + wr * (BM / 2) + m * 16 + rb + j;
                C[(size_t)row * ldc + col] = acc[m][n][j];
            }
        }
}

// ---------------------------------------------------------------------------
// Fused f32->bf16 cast of x, in_proj_w, out_proj_w.  (unchanged)
// ---------------------------------------------------------------------------
__global__ __launch_bounds__(256)
void cast3_kernel(const float* __restrict__ x, const float* __restrict__ w1,
                  const float* __restrict__ w2,
                  u16* __restrict__ xb, u16* __restrict__ w1b, u16* __restrict__ w2b) {
    int g = blockIdx.x * 256 + threadIdx.x;
    const float* src; u16* dst; int off;
    if (g < 131072)      { src = x;  dst = xb;  off = g; }
    else if (g < 262144) { src = w1; dst = w1b; off = g - 131072; }
    else                 { src = w2; dst = w2b; off = g - 262144; }
    float4 v0 = ((const float4*)src)[off * 2];
    float4 v1 = ((const float4*)src)[off * 2 + 1];
    u16x8 r;
    r[0] = f2bf(v0.x); r[1] = f2bf(v0.y); r[2] = f2bf(v0.z); r[3] = f2bf(v0.w);
    r[4] = f2bf(v1.x); r[5] = f2bf(v1.y); r[6] = f2bf(v1.z); r[7] = f2bf(v1.w);
    *(u16x8*)(dst + (size_t)off * 8) = r;
}

// ---------------------------------------------------------------------------
// Causal depthwise conv (4 taps) + SiLU on T layout: pure row streaming.
// xzT rows 0..1023 = xp channels.  Block = (l-half, d).
// ---------------------------------------------------------------------------
__global__ __launch_bounds__(256)
void conv_rows_kernel(const float* __restrict__ xzT,
                      const float* __restrict__ w,   // [1024][4]
                      const float* __restrict__ b,   // [1024]
                      float* __restrict__ xpcT) {
    const int d = blockIdx.y;
    const int l = blockIdx.x * 1024 + threadIdx.x * 4;
    const float4 wv = ((const float4*)w)[d];
    const float bias = b[d];
    const float* row = xzT + (size_t)d * L_SEQ;

    float4 cur  = *(const float4*)(row + l);
    float4 prev = (l == 0) ? make_float4(0.f, 0.f, 0.f, 0.f)
                           : *(const float4*)(row + l - 4);
    // e[i] = x[l-4+i]
    float e1 = prev.y, e2 = prev.z, e3 = prev.w;
    float e4 = cur.x, e5 = cur.y, e6 = cur.z, e7 = cur.w;
    float4 r;
    r.x = bias + wv.x * e1 + wv.y * e2 + wv.z * e3 + wv.w * e4;
    r.y = bias + wv.x * e2 + wv.y * e3 + wv.z * e4 + wv.w * e5;
    r.z = bias + wv.x * e3 + wv.y * e4 + wv.z * e5 + wv.w * e6;
    r.w = bias + wv.x * e4 + wv.y * e5 + wv.z * e6 + wv.w * e7;
    r.x = r.x / (1.f + __expf(-r.x));
    r.y = r.y / (1.f + __expf(-r.y));
    r.z = r.z / (1.f + __expf(-r.z));
    r.w = r.w / (1.f + __expf(-r.w));
    *(float4*)(xpcT + (size_t)d * L_SEQ + l) = r;
}

// ---------------------------------------------------------------------------
// x_proj on T layout: xdblT[e][l] = sum_k xw[e][k] * xpcT[k][l].
// Block = 8 l-columns; 256 thr = 2 K-halves x 64 e x 2 l-quads.
// w streamed as float4 (contiguous), x as broadcast f32x4 column loads.
// ---------------------------------------------------------------------------
__global__ __launch_bounds__(256)
void xproj_kernel(const float* __restrict__ xpcT,
                  const float* __restrict__ xw,    // [64][1024]
                  float* __restrict__ xdblT) {     // [64][2048]
    const int tid  = threadIdx.x;
    const int part = tid >> 7;          // 0..1 (K halves)
    const int e    = (tid >> 1) & 63;
    const int lc   = tid & 1;
    const int l0   = blockIdx.x * 8;

    const float* wrow = xw + (size_t)e * 1024 + part * 512;
    const float* xcol = xpcT + (size_t)part * 512 * L_SEQ + l0 + lc * 4;

    f32x4 acc = {0.f, 0.f, 0.f, 0.f};
#pragma unroll 4
    for (int k = 0; k < 512; k += 4) {
        float4 wv = *(const float4*)(wrow + k);
        f32x4 x0 = *(const f32x4*)(xcol + (size_t)(k + 0) * L_SEQ);
        f32x4 x1 = *(const f32x4*)(xcol + (size_t)(k + 1) * L_SEQ);
        f32x4 x2 = *(const f32x4*)(xcol + (size_t)(k + 2) * L_SEQ);
        f32x4 x3 = *(const f32x4*)(xcol + (size_t)(k + 3) * L_SEQ);
        acc += wv.x * x0 + wv.y * x1 + wv.z * x2 + wv.w * x3;
    }

    __shared__ f32x4 red[128];
    if (part == 1) red[(e << 1) | lc] = acc;
    __syncthreads();
    if (part == 0) {
        acc += red[(e << 1) | lc];
        *(f32x4*)(xdblT + (size_t)e * L_SEQ + l0 + lc * 4) = acc;
    }
}

// ---------------------------------------------------------------------------
// dt_proj + softplus (T layout).  (unchanged, verified)
// ---------------------------------------------------------------------------
__global__ __launch_bounds__(256)
void deltaT_kernel(const float* __restrict__ xdblT,
                   const float* __restrict__ dtw,   // [1024][32]
                   const float* __restrict__ dtb,
                   float* __restrict__ deltaT) {    // [1024][2048]
    const int tid = threadIdx.x;
    const int d0 = blockIdx.x * 64;
    const int l0 = blockIdx.y * 128;

    __shared__ float sx[32][128];
#pragma unroll
    for (int it = 0; it < 4; it++) {
        int idx = it * 256 + tid;
        int r  = idx >> 5;
        int c4 = (idx & 31) * 4;
        *(float4*)&sx[r][c4] = *(const float4*)(xdblT + (size_t)r * 2048 + l0 + c4);
    }

    const int dl = tid >> 2;
    const int lg = tid & 3;
    const int d  = d0 + dl;
    float wreg[32];
#pragma unroll
    for (int r4 = 0; r4 < 32; r4 += 4)
        *(float4*)&wreg[r4] = *(const float4*)(dtw + (size_t)d * 32 + r4);
    const float bias = dtb[d];
    __syncthreads();

#pragma unroll
    for (int j = 0; j < 8; j++) {
        float4 a = make_float4(bias, bias, bias, bias);
        const int col = j * 16 + lg * 4;
#pragma unroll
        for (int r = 0; r < 32; r++) {
            float4 v = *(const float4*)&sx[r][col];
            a.x = fmaf(wreg[r], v.x, a.x);
            a.y = fmaf(wreg[r], v.y, a.y);
            a.z = fmaf(wreg[r], v.z, a.z);
            a.w = fmaf(wreg[r], v.w, a.w);
        }
        float4 o;
        o.x = fmaxf(a.x, 0.f) + log1pf(expf(-fabsf(a.x)));
        o.y = fmaxf(a.y, 0.f) + log1pf(expf(-fabsf(a.y)));
        o.z = fmaxf(a.z, 0.f) + log1pf(expf(-fabsf(a.z)));
        o.w = fmaxf(a.w, 0.f) + log1pf(expf(-fabsf(a.w)));
        *(float4*)(deltaT + (size_t)d * 2048 + l0 + col) = o;
    }
}

// ---------------------------------------------------------------------------
// Chunked selective scan, 2 channels/block (512 blocks = 2 blocks/CU):
// wave = 2 L-subchunks x 2 ch x 16 states; 32 chunks x 64 steps.
// Math identical to the verified 3-phase formulation.  silu(z) applied
// in-kernel from xzT rows 1024+d (gzT eliminated).
// ---------------------------------------------------------------------------
#define NCHUNK 32

__global__ __launch_bounds__(1024)
void scan_kernel(const float* __restrict__ deltaT,
                 const float* __restrict__ xpcT,
                 const float* __restrict__ xzT,    // z rows at 1024+d
                 const float* __restrict__ xdblT,  // rows 32..47=B_T, 48..63=C_T
                 const float* __restrict__ A_log, const float* __restrict__ Dv,
                 u16* __restrict__ ypre) {
    const int tid   = threadIdx.x;
    const int lane  = tid & 63;
    const int chunk = ((tid >> 6) << 1) | (lane >> 5);   // 0..31
    const int dl    = (lane >> 4) & 1;
    const int n     = lane & 15;
    const int li    = (dl << 4) | n;
    const int d0    = blockIdx.x * 2;
    const int d     = d0 + dl;
    const int lb    = chunk * 64;

    const float Aneg = -__expf(A_log[d * D_STATE + n]);
    const float Dd   = Dv[d];

    const f32x4* dT4 = (const f32x4*)(deltaT + (size_t)d * L_SEQ + lb);
    const f32x4* xT4 = (const f32x4*)(xpcT   + (size_t)d * L_SEQ + lb);
    const f32x4* zT4 = (const f32x4*)(xzT    + (size_t)(1024 + d) * L_SEQ + lb);
    const f32x4* bT4 = (const f32x4*)(xdblT + (size_t)(32 + n) * L_SEQ + lb);
    const f32x4* cT4 = (const f32x4*)(xdblT + (size_t)(48 + n) * L_SEQ + lb);

    __shared__ float sLog[NCHUNK][32];
    __shared__ float sP[NCHUNK][32];
    __shared__ float sH[NCHUNK][32];
    __shared__ float s_y[L_SEQ][2];

    // ---- Phase A: chunk log-decay sum ----
    const float clipLog = -13.815511f;   // logf(1e-6f)
    float s = 0.f;
#pragma unroll 8
    for (int i = 0; i < 16; i++) {
        f32x4 d4 = dT4[i];
#pragma unroll
        for (int k = 0; k < 4; k++) s += fmaxf(d4[k] * Aneg, clipLog);
    }
    sLog[chunk][li] = s;
    sP[chunk][li]   = __expf(s);
    __syncthreads();

    float lsum = 0.f;
    for (int v = 0; v < chunk; v++) lsum += sLog[v][li];
    const float cAs = __expf(lsum);

    // ---- Phase B: local accumulation with known cA_start ----
    float hloc = 0.f, cA = cAs;
    for (int i = 0; i < 16; i++) {
        f32x4 d4 = dT4[i], x4 = xT4[i], b4 = bT4[i];
#pragma unroll
        for (int k = 0; k < 4; k++) {
            float dA = fmaxf(__expf(d4[k] * Aneg), 1e-6f);
            float g  = cA * __builtin_amdgcn_rcpf(cA + 1e-8f);
            hloc = dA * hloc + (dA * g) * (d4[k] * b4[k] * x4[k]);
            cA *= dA;
        }
    }
    sH[chunk][li] = hloc;
    __syncthreads();

    float h = 0.f;
    for (int v = 0; v < chunk; v++) h = sP[v][li] * h + sH[v][li];

    // ---- Phase C: full recurrence + output ----
    cA = cAs;
    for (int i = 0; i < 16; i++) {
        f32x4 d4 = dT4[i], x4 = xT4[i], b4 = bT4[i], c4 = cT4[i];
        f32x4 z4 = zT4[i];
#pragma unroll
        for (int k = 0; k < 4; k++) {
            float dA = fmaxf(__expf(d4[k] * Aneg), 1e-6f);
            float g  = cA * __builtin_amdgcn_rcpf(cA + 1e-8f);
            h  = dA * h + (dA * g) * (d4[k] * b4[k] * x4[k]);
            cA *= dA;
            float p = h * c4[k];
            p += __shfl_xor(p, 1);
            p += __shfl_xor(p, 2);
            p += __shfl_xor(p, 4);
            p += __shfl_xor(p, 8);
            if (n == 0) {
                float sz = z4[k] * __builtin_amdgcn_rcpf(1.f + __expf(-z4[k]));
                s_y[lb + 4 * i + k][dl] = (p + x4[k] * Dd) * sz;
            }
        }
    }
    __syncthreads();

    for (int l = tid; l < L_SEQ; l += 1024) {
        ushort2 o;
        o.x = f2bf(s_y[l][0]);
        o.y = f2bf(s_y[l][1]);
        *(ushort2*)(ypre + (size_t)l * D_INNER + d0) = o;
    }
}

// ---------------------------------------------------------------------------
extern "C" void kernel_launch(void* const* d_in, const int* in_sizes, int n_in,
                              void* d_out, int out_size, void* d_ws, size_t ws_size,
                              hipStream_t stream) {
    const float* x          = (const float*)d_in[0];
    const float* in_proj_w  = (const float*)d_in[1];
    const float* conv_w     = (const float*)d_in[2];
    const float* conv_b     = (const float*)d_in[3];
    const float* x_proj_w   = (const float*)d_in[4];
    const float* dt_proj_w  = (const float*)d_in[5];
    const float* dt_proj_b  = (const float*)d_in[6];
    const float* A_log      = (const float*)d_in[7];
    const float* Dv         = (const float*)d_in[8];
    const float* out_proj_w = (const float*)d_in[9];
    float* out = (float*)d_out;
    float* ws  = (float*)d_ws;

    // workspace (float offsets):
    float* xzT    = ws;                        // [2048 e][2048 l] f32 (live thru scan)
    float* xpcT   = ws + 4194304;              // [1024][2048] f32
    float* deltaT = ws + 6291456;              // [1024][2048] f32
    float* xdblT  = ws + 8388608;              // [64][2048]   f32
    u16*   ypre   = (u16*)(ws + 8519680);      // [2048][1024] bf16
    u16*   xb     = (u16*)(ws + 9568256);      // [2048][512]  bf16
    u16*   w1b    = (u16*)(ws + 10092544);     // [2048][512]  bf16
    u16*   w2b    = (u16*)(ws + 10616832);     // [512][1024]  bf16

    // 0. cast x, in_proj_w, out_proj_w to bf16
    cast3_kernel<<<1280, 256, 0, stream>>>(x, in_proj_w, out_proj_w, xb, w1b, w2b);

    // 1. in_proj, transposed output: xzT[e][l] = in_proj_w @ x^T  (swap operands)
    gemm_mfma_nt<128, 128><<<dim3(2048 / 128, 2048 / 128), 256, 0, stream>>>(
        w1b, xb, xzT, 2 * D_INNER, L_SEQ, D_MODEL, L_SEQ);

    // 2. conv + silu on rows -> xpcT
    conv_rows_kernel<<<dim3(2, 1024), 256, 0, stream>>>(xzT, conv_w, conv_b, xpcT);

    // 3. x_proj -> xdblT (rows 0..31 dt-rank, 32..47 B_T, 48..63 C_T)
    xproj_kernel<<<256, 256, 0, stream>>>(xpcT, x_proj_w, xdblT);

    // 4. dt_proj + softplus -> deltaT
    deltaT_kernel<<<dim3(16, 16), 256, 0, stream>>>(xdblT, dt_proj_w, dt_proj_b,
                                                    deltaT);

    // 5. chunked selective scan (+ D skip, * silu(z)) -> bf16 ypre
    scan_kernel<<<512, 1024, 0, stream>>>(deltaT, xpcT, xzT, xdblT,
                                          A_log, Dv, ypre);

    // 6. out_proj (bf16 MFMA): out = ypre @ out_proj_w^T (M=2048,N=512,K=1024)
    gemm_mfma_nt<64, 64><<<dim3(512 / 64, 2048 / 64), 256, 0, stream>>>(
        ypre, w2b, out, L_SEQ, D_MODEL, D_INNER, D_MODEL);
}